// Round 2
// baseline (385.767 us; speedup 1.0000x reference)
//
#include <hip/hip_runtime.h>
#include <hip/hip_bf16.h>
#include <math.h>

#define B_ 2
#define S_ 2048
#define D_ 1024
#define H_ 16
#define HD_ 64

typedef short bf16x8 __attribute__((ext_vector_type(8)));
typedef short bf16x4 __attribute__((ext_vector_type(4)));
typedef float f32x4 __attribute__((ext_vector_type(4)));

#define MFMA32(a, b, c) __builtin_amdgcn_mfma_f32_16x16x32_bf16(a, b, c, 0, 0, 0)
#define MFMA16(a, b, c) __builtin_amdgcn_mfma_f32_16x16x16bf16_1k(a, b, c, 0, 0, 0)

static __device__ __forceinline__ unsigned short f2bf(float f) {
    union { float f; unsigned u; } v = {f};
    return (unsigned short)((v.u + 0x7fffu + ((v.u >> 16) & 1u)) >> 16);
}

static __device__ __forceinline__ unsigned pk2bf(float a, float b) {
    __hip_bfloat162 h = __float22bfloat162_rn(make_float2(a, b));
    unsigned r;
    __builtin_memcpy(&r, &h, 4);
    return r;
}

static __device__ __forceinline__ void gl2lds16(const void* g, void* l) {
    __builtin_amdgcn_global_load_lds((const __attribute__((address_space(1))) unsigned int*)g,
                                     (__attribute__((address_space(3))) unsigned int*)l,
                                     16, 0, 0);
}

// scale all 8 bf16 lanes of a fragment by s (fp32 math, RNE repack)
static __device__ __forceinline__ bf16x8 scaleQ(bf16x8 v, float s) {
    union { bf16x8 v; unsigned u[4]; } a, r;
    a.v = v;
    #pragma unroll
    for (int i = 0; i < 4; ++i) {
        float lo = __uint_as_float(a.u[i] << 16);
        float hi = __uint_as_float(a.u[i] & 0xffff0000u);
        r.u[i] = pk2bf(lo * s, hi * s);
    }
    return r.v;
}

// ---------------------------------------------------------------------------
// fused fp32 -> bf16 convert for all three inputs (RNE)
// ---------------------------------------------------------------------------
__global__ __launch_bounds__(256) void cvt_all(const float* __restrict__ x,
                                               const float* __restrict__ wq,
                                               const float* __restrict__ wo,
                                               unsigned short* __restrict__ xb,
                                               unsigned short* __restrict__ wqb,
                                               unsigned short* __restrict__ wob) {
    const int N0 = 1048576, N1 = 786432, N2 = 262144;  // float4 counts
    int stride = gridDim.x * blockDim.x;
    for (int i = blockIdx.x * blockDim.x + threadIdx.x; i < N0 + N1 + N2; i += stride) {
        const float4* src; ushort4* dst; int j;
        if (i < N0)            { src = (const float4*)x;  dst = (ushort4*)xb;  j = i; }
        else if (i < N0 + N1)  { src = (const float4*)wq; dst = (ushort4*)wqb; j = i - N0; }
        else                   { src = (const float4*)wo; dst = (ushort4*)wob; j = i - N0 - N1; }
        float4 v = src[j];
        ushort4 o;
        o.x = f2bf(v.x); o.y = f2bf(v.y); o.z = f2bf(v.z); o.w = f2bf(v.w);
        dst[j] = o;
    }
}

// ---------------------------------------------------------------------------
// bf16 NT GEMM, m97-style: global_load_lds(16B) staging, BM=128, BK=32,
// 256 threads. BN=128: waves 2x2 (64x64 each). BN=64: waves 4x1 (32x64).
// ---------------------------------------------------------------------------
template <int BN>
__global__ __launch_bounds__(256) void gemm_nt_b(const unsigned short* __restrict__ A,
                                                 const unsigned short* __restrict__ Bm,
                                                 void* __restrict__ Cout,
                                                 int M, int N, int K, int c_bf16) {
    constexpr int BM = 128, BK = 32;
    constexpr int MI = (BN == 128) ? 4 : 2;
    constexpr int NI = 4;
    constexpr int SEGS = (BM + BN) / 16;
    __shared__ unsigned short As[BM * BK];
    __shared__ unsigned short Bs[BN * BK];

    const int tid = threadIdx.x;
    const int wave = tid >> 6, lane = tid & 63;
    const int m16 = lane & 15, quad = lane >> 4;
    const int wrow = (BN == 128) ? (wave >> 1) * 64 : wave * 32;
    const int wcol = (BN == 128) ? (wave & 1) * 64 : 0;
    const int row0 = blockIdx.y * BM, col0 = blockIdx.x * BN;

    const int lrow = lane >> 2;
    const int lk = (lane & 3) * 8;

    f32x4 acc[MI][NI] = {};

    for (int k0 = 0; k0 < K; k0 += BK) {
        __syncthreads();
        for (int s = wave; s < SEGS; s += 4) {
            if (s < BM / 16) {
                gl2lds16(&A[(size_t)(row0 + s * 16 + lrow) * K + k0 + lk],
                         &As[s * 16 * BK]);
            } else {
                int t = s - BM / 16;
                gl2lds16(&Bm[(size_t)(col0 + t * 16 + lrow) * K + k0 + lk],
                         &Bs[t * 16 * BK]);
            }
        }
        __asm__ volatile("s_waitcnt vmcnt(0)" ::: "memory");
        __syncthreads();

        bf16x8 af[MI], bfr[NI];
        #pragma unroll
        for (int mi = 0; mi < MI; ++mi)
            af[mi] = *(const bf16x8*)&As[(wrow + mi * 16 + m16) * BK + quad * 8];
        #pragma unroll
        for (int ni = 0; ni < NI; ++ni)
            bfr[ni] = *(const bf16x8*)&Bs[(wcol + ni * 16 + m16) * BK + quad * 8];
        #pragma unroll
        for (int mi = 0; mi < MI; ++mi)
            #pragma unroll
            for (int ni = 0; ni < NI; ++ni)
                acc[mi][ni] = MFMA32(af[mi], bfr[ni], acc[mi][ni]);
    }

    #pragma unroll
    for (int mi = 0; mi < MI; ++mi) {
        #pragma unroll
        for (int r = 0; r < 4; ++r) {
            size_t grow = row0 + wrow + mi * 16 + quad * 4 + r;
            #pragma unroll
            for (int ni = 0; ni < NI; ++ni) {
                size_t gcol = col0 + wcol + ni * 16 + m16;
                if (c_bf16)
                    ((unsigned short*)Cout)[grow * N + gcol] = f2bf(acc[mi][ni][r]);
                else
                    ((float*)Cout)[grow * N + gcol] = acc[mi][ni][r];
            }
        }
    }
}

// ---------------------------------------------------------------------------
// V transpose: qkv V-section [b][s][h*64+d] -> vT[(b*16+h)*64 + d][s]
// grid 1024 (32 bh x 32 s-tiles), 256 threads, LDS 64x64 tile (+pad).
// ---------------------------------------------------------------------------
__global__ __launch_bounds__(256) void transpose_v(const unsigned short* __restrict__ qkv,
                                                   unsigned short* __restrict__ vt) {
    __shared__ unsigned short T[64 * 72];
    const int bid = blockIdx.x;
    const int bh = bid & 31, st = bid >> 5;
    const int b = bh >> 4, h = bh & 15;
    const int tid = threadIdx.x;

    #pragma unroll
    for (int i = 0; i < 2; ++i) {
        int idx = tid + i * 256;
        int r = idx >> 3, c8 = (idx & 7) * 8;
        *(uint4*)&T[r * 72 + c8] =
            *(const uint4*)(qkv + (size_t)(b * S_ + st * 64 + r) * (3 * D_) + 2 * D_ + h * HD_ + c8);
    }
    __syncthreads();
    #pragma unroll
    for (int i = 0; i < 2; ++i) {
        int idx = tid + i * 256;
        int d = idx >> 3, s8 = (idx & 7) * 8;
        unsigned short a[8];
        #pragma unroll
        for (int j = 0; j < 8; ++j) a[j] = T[(s8 + j) * 72 + d];
        *(uint4*)(vt + ((size_t)bh * 64 + d) * S_ + st * 64 + s8) = *(uint4*)a;
    }
}

// ---------------------------------------------------------------------------
// MFMA flash attention, KT=128, 8 waves x 16 q (512 thr).
// K: DMA-staged in LDS, XOR-swizzled, double-buffered (16 KB x 2).
// V: read DIRECTLY from global vt (L1-resident 16 KB tile, TA/TD pipe) --
//    removes half the LDS read traffic and the V bank conflicts that
//    saturated the per-CU LDS pipe in the previous version.
// Q pre-scaled by 0.125*log2e -> p = exp2(z). lsum via ones-MFMA.
// ---------------------------------------------------------------------------
__global__ __launch_bounds__(512, 4) void attn_mfma(const unsigned short* __restrict__ qkv,
                                                    const unsigned short* __restrict__ vt,
                                                    unsigned short* __restrict__ out) {
    __shared__ unsigned short Ks[2][128 * 64];  // [key][hd-chunk ^ (key&7)]

    const int id = blockIdx.x;
    const int bh = ((id >> 3) & 3) * 8 + (id & 7);
    const int b = bh >> 4, h = bh & 15;
    const int q0 = (id >> 5) * 128;

    const int tid = threadIdx.x;
    const int wave = tid >> 6, lane = tid & 63;  // wave 0..7
    const int m16 = lane & 15, quad = lane >> 4;

    const float QS = 0.125f * 1.44269504089f;  // scale * log2(e), folded into Q

    bf16x8 qf0, qf1;
    {
        const unsigned short* qrow =
            qkv + ((size_t)b * S_ + q0 + wave * 16 + m16) * (3 * D_) + h * HD_;
        qf0 = scaleQ(*(const bf16x8*)(qrow + quad * 8), QS);
        qf1 = scaleQ(*(const bf16x8*)(qrow + 32 + quad * 8), QS);
    }

    f32x4 o[4] = {};
    f32x4 ol = {};
    const bf16x4 onesf = {(short)0x3F80, (short)0x3F80, (short)0x3F80, (short)0x3F80};

    const unsigned short* kbase = qkv + (size_t)b * S_ * 3 * D_ + D_ + h * HD_;
    const unsigned short* vtbase = vt + (size_t)bh * 64 * S_;

    const int lr8 = lane >> 3;           // row-in-8-group
    const int lsrc = (lane & 7) ^ lr8;   // source chunk for swizzled DMA

    // K DMA: 16 segs of 1 KB per 128-key tile; each wave issues 2
    auto issueDMA = [&](int t, int buf) {
        const unsigned short* kt = kbase + (size_t)t * 128 * (3 * D_);
        #pragma unroll
        for (int i = 0; i < 2; ++i) {
            int gi = wave * 2 + i;                      // 0..15
            int r = gi * 8 + lr8;                       // key row 0..127
            gl2lds16(kt + (size_t)r * (3 * D_) + lsrc * 8, &Ks[buf][gi * 512]);
        }
    };

    issueDMA(0, 0);
    __asm__ volatile("s_waitcnt vmcnt(0)" ::: "memory");
    __syncthreads();
    issueDMA(1, 1);

    for (int t = 0; t < S_ / 128; ++t) {
        const int buf = t & 1;

        #pragma unroll
        for (int h2 = 0; h2 < 2; ++h2) {
            const unsigned short* Kp = &Ks[buf][h2 * 4096];

            // V fragments direct from global (L1-served after first touch).
            // Issued first so QK^T + exp2 covers their latency.
            bf16x4 vf[4][4];
            #pragma unroll
            for (int dt = 0; dt < 4; ++dt)
                #pragma unroll
                for (int nt = 0; nt < 4; ++nt)
                    vf[dt][nt] = *(const bf16x4*)(vtbase + (size_t)(dt * 16 + m16) * S_ +
                                                  t * 128 + h2 * 64 + nt * 16 + quad * 4);

            // S^T = K·Q^T, p = exp2(z), pack into K=16 A-frags
            bf16x4 pf[4];
            #pragma unroll
            for (int nt = 0; nt < 4; ++nt) {
                int a0 = (nt * 16 + m16) * 64 + ((quad ^ (m16 & 7)) * 8);
                bf16x8 kf0 = *(const bf16x8*)&Kp[a0];
                bf16x8 kf1 = *(const bf16x8*)&Kp[a0 ^ 32];
                f32x4 z = {0.f, 0.f, 0.f, 0.f};
                z = MFMA32(kf0, qf0, z);
                z = MFMA32(kf1, qf1, z);
                float p0 = __builtin_amdgcn_exp2f(z[0]);
                float p1 = __builtin_amdgcn_exp2f(z[1]);
                float p2 = __builtin_amdgcn_exp2f(z[2]);
                float p3 = __builtin_amdgcn_exp2f(z[3]);
                union { unsigned u[2]; bf16x4 v; } pk;
                pk.u[0] = pk2bf(p0, p1);
                pk.u[1] = pk2bf(p2, p3);
                pf[nt] = pk.v;
                ol = MFMA16(pf[nt], onesf, ol);  // row-sum of same rounded p
            }

            // O += P·V via 16x16x16 (V from registers)
            #pragma unroll
            for (int nt = 0; nt < 4; ++nt)
                #pragma unroll
                for (int dt = 0; dt < 4; ++dt)
                    o[dt] = MFMA16(pf[nt], vf[dt][nt], o[dt]);
        }

        // DMA(t+1) had the whole compute(t) to land; sync; refill freed buf
        __asm__ volatile("s_waitcnt vmcnt(0)" ::: "memory");
        __syncthreads();
        if (t + 2 < S_ / 128) issueDMA(t + 2, buf);
    }

    // epilogue: ol[r] = row-sum replicated across cols
    #pragma unroll
    for (int r = 0; r < 4; ++r) {
        float inv = 1.f / ol[r];
        size_t row = (size_t)b * S_ + q0 + wave * 16 + quad * 4 + r;
        unsigned short* op = out + row * D_ + h * HD_;
        #pragma unroll
        for (int dt = 0; dt < 4; ++dt)
            op[dt * 16 + m16] = f2bf(o[dt][r] * inv);
    }
}

// ---------------------------------------------------------------------------
extern "C" void kernel_launch(void* const* d_in, const int* in_sizes, int n_in,
                              void* d_out, int out_size, void* d_ws, size_t ws_size,
                              hipStream_t stream) {
    const float* x     = (const float*)d_in[0];
    const float* w_qkv = (const float*)d_in[1];
    const float* w_out = (const float*)d_in[2];
    float* out = (float*)d_out;

    const size_t n_x = (size_t)B_ * S_ * D_;
    const size_t n_wqkv = (size_t)3 * D_ * D_;
    const size_t n_wout = (size_t)D_ * D_;

    unsigned short* xb    = (unsigned short*)d_ws;
    unsigned short* wqkvb = xb + n_x;
    unsigned short* woutb = wqkvb + n_wqkv;
    unsigned short* qkvb  = woutb + n_wout;                    // [B,S,3D]
    unsigned short* attnb = qkvb + (size_t)B_ * S_ * 3 * D_;   // [B,S,D]
    unsigned short* vtb   = attnb + n_x;                       // [B*H*64, S]

    dim3 blk(256);

    cvt_all<<<2048, blk, 0, stream>>>(x, w_qkv, w_out, xb, wqkvb, woutb);

    // qkv = x @ w_qkv^T : M=4096, N=3072, K=1024 (bf16 out)
    gemm_nt_b<128><<<dim3(3 * D_ / 128, B_ * S_ / 128), blk, 0, stream>>>(
        xb, wqkvb, qkvb, B_ * S_, 3 * D_, D_, 1);

    // V transpose for DMA-friendly attention staging
    transpose_v<<<1024, blk, 0, stream>>>(qkvb, vtb);

    // attention: 512 XCD-swizzled blocks of 128 queries, 8 waves x 16 q
    attn_mfma<<<512, dim3(512), 0, stream>>>(qkvb, vtb, attnb);

    // out = attn_out @ w_out^T : M=4096, N=1024, K=1024 (fp32 out, BN=64)
    gemm_nt_b<64><<<dim3(D_ / 64, B_ * S_ / 128), blk, 0, stream>>>(
        attnb, woutb, out, B_ * S_, D_, D_, 0);
}

// Round 3
// 197.855 us; speedup vs baseline: 1.9497x; 1.9497x over previous
//
#include <hip/hip_runtime.h>
#include <hip/hip_bf16.h>
#include <math.h>

#define B_ 2
#define S_ 2048
#define D_ 1024
#define H_ 16
#define HD_ 64

typedef short bf16x8 __attribute__((ext_vector_type(8)));
typedef short bf16x4 __attribute__((ext_vector_type(4)));
typedef float f32x4 __attribute__((ext_vector_type(4)));

#define MFMA32(a, b, c) __builtin_amdgcn_mfma_f32_16x16x32_bf16(a, b, c, 0, 0, 0)
#define MFMA16(a, b, c) __builtin_amdgcn_mfma_f32_16x16x16bf16_1k(a, b, c, 0, 0, 0)

static __device__ __forceinline__ unsigned short f2bf(float f) {
    union { float f; unsigned u; } v = {f};
    return (unsigned short)((v.u + 0x7fffu + ((v.u >> 16) & 1u)) >> 16);
}

static __device__ __forceinline__ unsigned pk2bf(float a, float b) {
    __hip_bfloat162 h = __float22bfloat162_rn(make_float2(a, b));
    unsigned r;
    __builtin_memcpy(&r, &h, 4);
    return r;
}

static __device__ __forceinline__ void gl2lds16(const void* g, void* l) {
    __builtin_amdgcn_global_load_lds((const __attribute__((address_space(1))) unsigned int*)g,
                                     (__attribute__((address_space(3))) unsigned int*)l,
                                     16, 0, 0);
}

// scale all 8 bf16 lanes of a fragment by s (fp32 math, RNE repack)
static __device__ __forceinline__ bf16x8 scaleQ(bf16x8 v, float s) {
    union { bf16x8 v; unsigned u[4]; } a, r;
    a.v = v;
    #pragma unroll
    for (int i = 0; i < 4; ++i) {
        float lo = __uint_as_float(a.u[i] << 16);
        float hi = __uint_as_float(a.u[i] & 0xffff0000u);
        r.u[i] = pk2bf(lo * s, hi * s);
    }
    return r.v;
}

// ---------------------------------------------------------------------------
// fused fp32 -> bf16 convert for all three inputs (RNE)
// ---------------------------------------------------------------------------
__global__ __launch_bounds__(256) void cvt_all(const float* __restrict__ x,
                                               const float* __restrict__ wq,
                                               const float* __restrict__ wo,
                                               unsigned short* __restrict__ xb,
                                               unsigned short* __restrict__ wqb,
                                               unsigned short* __restrict__ wob) {
    const int N0 = 1048576, N1 = 786432, N2 = 262144;  // float4 counts
    int stride = gridDim.x * blockDim.x;
    for (int i = blockIdx.x * blockDim.x + threadIdx.x; i < N0 + N1 + N2; i += stride) {
        const float4* src; ushort4* dst; int j;
        if (i < N0)            { src = (const float4*)x;  dst = (ushort4*)xb;  j = i; }
        else if (i < N0 + N1)  { src = (const float4*)wq; dst = (ushort4*)wqb; j = i - N0; }
        else                   { src = (const float4*)wo; dst = (ushort4*)wob; j = i - N0 - N1; }
        float4 v = src[j];
        ushort4 o;
        o.x = f2bf(v.x); o.y = f2bf(v.y); o.z = f2bf(v.z); o.w = f2bf(v.w);
        dst[j] = o;
    }
}

// ---------------------------------------------------------------------------
// bf16 NT GEMM, m97-style: global_load_lds(16B) staging, BM=128, BK=32,
// 256 threads. BN=128: waves 2x2 (64x64 each). BN=64: waves 4x1 (32x64).
// ---------------------------------------------------------------------------
template <int BN>
__global__ __launch_bounds__(256) void gemm_nt_b(const unsigned short* __restrict__ A,
                                                 const unsigned short* __restrict__ Bm,
                                                 void* __restrict__ Cout,
                                                 int M, int N, int K, int c_bf16) {
    constexpr int BM = 128, BK = 32;
    constexpr int MI = (BN == 128) ? 4 : 2;
    constexpr int NI = 4;
    constexpr int SEGS = (BM + BN) / 16;
    __shared__ unsigned short As[BM * BK];
    __shared__ unsigned short Bs[BN * BK];

    const int tid = threadIdx.x;
    const int wave = tid >> 6, lane = tid & 63;
    const int m16 = lane & 15, quad = lane >> 4;
    const int wrow = (BN == 128) ? (wave >> 1) * 64 : wave * 32;
    const int wcol = (BN == 128) ? (wave & 1) * 64 : 0;
    const int row0 = blockIdx.y * BM, col0 = blockIdx.x * BN;

    const int lrow = lane >> 2;
    const int lk = (lane & 3) * 8;

    f32x4 acc[MI][NI] = {};

    for (int k0 = 0; k0 < K; k0 += BK) {
        __syncthreads();
        for (int s = wave; s < SEGS; s += 4) {
            if (s < BM / 16) {
                gl2lds16(&A[(size_t)(row0 + s * 16 + lrow) * K + k0 + lk],
                         &As[s * 16 * BK]);
            } else {
                int t = s - BM / 16;
                gl2lds16(&Bm[(size_t)(col0 + t * 16 + lrow) * K + k0 + lk],
                         &Bs[t * 16 * BK]);
            }
        }
        __asm__ volatile("s_waitcnt vmcnt(0)" ::: "memory");
        __syncthreads();

        bf16x8 af[MI], bfr[NI];
        #pragma unroll
        for (int mi = 0; mi < MI; ++mi)
            af[mi] = *(const bf16x8*)&As[(wrow + mi * 16 + m16) * BK + quad * 8];
        #pragma unroll
        for (int ni = 0; ni < NI; ++ni)
            bfr[ni] = *(const bf16x8*)&Bs[(wcol + ni * 16 + m16) * BK + quad * 8];
        #pragma unroll
        for (int mi = 0; mi < MI; ++mi)
            #pragma unroll
            for (int ni = 0; ni < NI; ++ni)
                acc[mi][ni] = MFMA32(af[mi], bfr[ni], acc[mi][ni]);
    }

    #pragma unroll
    for (int mi = 0; mi < MI; ++mi) {
        #pragma unroll
        for (int r = 0; r < 4; ++r) {
            size_t grow = row0 + wrow + mi * 16 + quad * 4 + r;
            #pragma unroll
            for (int ni = 0; ni < NI; ++ni) {
                size_t gcol = col0 + wcol + ni * 16 + m16;
                if (c_bf16)
                    ((unsigned short*)Cout)[grow * N + gcol] = f2bf(acc[mi][ni][r]);
                else
                    ((float*)Cout)[grow * N + gcol] = acc[mi][ni][r];
            }
        }
    }
}

// ---------------------------------------------------------------------------
// V transpose: qkv V-section [b][s][h*64+d] -> vT[(b*16+h)*64 + d][s]
// grid 1024 (32 bh x 32 s-tiles), 256 threads, LDS 64x64 tile (+pad).
// ---------------------------------------------------------------------------
__global__ __launch_bounds__(256) void transpose_v(const unsigned short* __restrict__ qkv,
                                                   unsigned short* __restrict__ vt) {
    __shared__ unsigned short T[64 * 72];
    const int bid = blockIdx.x;
    const int bh = bid & 31, st = bid >> 5;
    const int b = bh >> 4, h = bh & 15;
    const int tid = threadIdx.x;

    #pragma unroll
    for (int i = 0; i < 2; ++i) {
        int idx = tid + i * 256;
        int r = idx >> 3, c8 = (idx & 7) * 8;
        *(uint4*)&T[r * 72 + c8] =
            *(const uint4*)(qkv + (size_t)(b * S_ + st * 64 + r) * (3 * D_) + 2 * D_ + h * HD_ + c8);
    }
    __syncthreads();
    #pragma unroll
    for (int i = 0; i < 2; ++i) {
        int idx = tid + i * 256;
        int d = idx >> 3, s8 = (idx & 7) * 8;
        unsigned short a[8];
        #pragma unroll
        for (int j = 0; j < 8; ++j) a[j] = T[(s8 + j) * 72 + d];
        *(uint4*)(vt + ((size_t)bh * 64 + d) * S_ + st * 64 + s8) = *(uint4*)a;
    }
}

// ---------------------------------------------------------------------------
// MFMA flash attention, key-split wave groups.
// 512 threads = 8 waves. Waves 0-3 (group A) own q-subtiles of 32 queries
// and process EVEN 64-key tiles; waves 4-7 (group B) own the SAME queries
// and process ODD tiles. Each wave amortizes each staged K/V tile over 32
// queries -> per-CU LDS read bytes HALVED vs 16q/wave (the R1 LDS-BW
// bound). KT=64: live set = 2 tiles x 16KB x 2 bufs = 64KB -> 2 blocks/CU,
// 4 waves/SIMD. No running max (exp2 direct), so partials merge by pure
// addition: group B writes (o,ol) to LDS once; group A adds + normalizes.
// K/V both LDS-staged via global_load_lds with XOR source-swizzle
// (R2 lesson: scattered per-lane global fragment loads are 16x worse).
// Pipeline = proven R1 pattern: compute(t) with DMA(t+1) in flight;
// vmcnt(0); barrier; issue DMA(t+2).
// ---------------------------------------------------------------------------
__global__ __launch_bounds__(512, 4) void attn_mfma(const unsigned short* __restrict__ qkv,
                                                    const unsigned short* __restrict__ vt,
                                                    unsigned short* __restrict__ out) {
    // [buf][ K_even(4096) | V_even(4096) | K_odd(4096) | V_odd(4096) ] shorts
    __shared__ unsigned short L[2][16384];

    const int id = blockIdx.x;
    const int bh = ((id >> 3) & 3) * 8 + (id & 7);
    const int b = bh >> 4, h = bh & 15;
    const int q0 = (id >> 5) * 128;

    const int tid = threadIdx.x;
    const int wave = tid >> 6, lane = tid & 63;  // wave 0..7
    const int grp = wave >> 2;                   // 0: even tiles, 1: odd tiles
    const int qw = wave & 3;                     // q-subtile (32 q each)
    const int m16 = lane & 15, quad = lane >> 4;

    const float QS = 0.125f * 1.44269504089f;  // scale * log2(e), folded into Q

    bf16x8 qf0[2], qf1[2];
    #pragma unroll
    for (int g = 0; g < 2; ++g) {
        const unsigned short* qrow =
            qkv + ((size_t)b * S_ + q0 + qw * 32 + g * 16 + m16) * (3 * D_) + h * HD_;
        qf0[g] = scaleQ(*(const bf16x8*)(qrow + quad * 8), QS);
        qf1[g] = scaleQ(*(const bf16x8*)(qrow + 32 + quad * 8), QS);
    }

    f32x4 o[2][4] = {};
    f32x4 ol[2] = {};
    const bf16x4 onesf = {(short)0x3F80, (short)0x3F80, (short)0x3F80, (short)0x3F80};

    const unsigned short* kbase = qkv + (size_t)b * S_ * 3 * D_ + D_ + h * HD_;
    const unsigned short* vtbase = vt + (size_t)bh * 64 * S_;

    const int lr8 = lane >> 3;           // row-in-8-group
    const int lsrc = (lane & 7) ^ lr8;   // source chunk for swizzled DMA

    // loop-invariant LDS read offsets (shorts, within a 4096-short region)
    const int kaddr0 = m16 * 64 + ((quad ^ (m16 & 7)) * 8);
    const int kaddr1 = kaddr0 ^ 32;
    int va[4];
    #pragma unroll
    for (int nt = 0; nt < 4; ++nt) {
        int kc = nt * 2 + (quad >> 1);
        va[nt] = m16 * 64 + ((kc ^ (m16 & 7)) * 8) + (quad & 1) * 4;
    }

    // stage tile pair {2*pair, 2*pair+1}: 32 segs of 1KB, 4 per wave.
    // waves 0,1: K_even  2,3: V_even  4,5: K_odd  6,7: V_odd
    auto issueDMA = [&](int pair, int buf) {
        const int mat = wave >> 1;              // 0..3
        const int tt = pair * 2 + (mat >> 1);   // 64-key tile index
        unsigned short* dstb = &L[buf][mat * 4096];
        if ((mat & 1) == 0) {
            const unsigned short* kt = kbase + (size_t)tt * 64 * (3 * D_);
            #pragma unroll
            for (int i = 0; i < 4; ++i) {
                int gi = (wave & 1) * 4 + i;    // seg 0..7
                gl2lds16(kt + (size_t)(gi * 8 + lr8) * (3 * D_) + lsrc * 8,
                         dstb + gi * 512);
            }
        } else {
            const unsigned short* vtt = vtbase + tt * 64;
            #pragma unroll
            for (int i = 0; i < 4; ++i) {
                int gi = (wave & 1) * 4 + i;    // d-row group 0..7
                gl2lds16(vtt + (size_t)(gi * 8 + lr8) * S_ + lsrc * 8,
                         dstb + gi * 512);
            }
        }
    };

    issueDMA(0, 0);
    __asm__ volatile("s_waitcnt vmcnt(0)" ::: "memory");
    __syncthreads();
    issueDMA(1, 1);

    for (int s = 0; s < 16; ++s) {
        const int buf = s & 1;
        const unsigned short* Kp = &L[buf][grp * 8192];
        const unsigned short* Vp = Kp + 4096;

        // S^T = K·Q^T over this wave's 64-key tile, p = exp2(z)
        bf16x4 pf[2][4];
        #pragma unroll
        for (int nt = 0; nt < 4; ++nt) {
            bf16x8 kf0 = *(const bf16x8*)&Kp[kaddr0 + nt * 1024];
            bf16x8 kf1 = *(const bf16x8*)&Kp[kaddr1 + nt * 1024];
            #pragma unroll
            for (int g = 0; g < 2; ++g) {
                f32x4 z = {0.f, 0.f, 0.f, 0.f};
                z = MFMA32(kf0, qf0[g], z);
                z = MFMA32(kf1, qf1[g], z);
                float p0 = __builtin_amdgcn_exp2f(z[0]);
                float p1 = __builtin_amdgcn_exp2f(z[1]);
                float p2 = __builtin_amdgcn_exp2f(z[2]);
                float p3 = __builtin_amdgcn_exp2f(z[3]);
                union { unsigned u[2]; bf16x4 v; } pk;
                pk.u[0] = pk2bf(p0, p1);
                pk.u[1] = pk2bf(p2, p3);
                pf[g][nt] = pk.v;
                ol[g] = MFMA16(pf[g][nt], onesf, ol[g]);  // row-sum of rounded p
            }
        }

        // O += P·V via 16x16x16
        #pragma unroll
        for (int nt = 0; nt < 4; ++nt)
            #pragma unroll
            for (int dt = 0; dt < 4; ++dt) {
                bf16x4 vf = *(const bf16x4*)&Vp[va[nt] + dt * 1024];
                o[0][dt] = MFMA16(pf[0][nt], vf, o[0][dt]);
                o[1][dt] = MFMA16(pf[1][nt], vf, o[1][dt]);
            }

        // DMA(s+1) had all of compute(s) to land; drain; refill freed buf
        __asm__ volatile("s_waitcnt vmcnt(0)" ::: "memory");
        __syncthreads();
        if (s + 2 < 16) issueDMA(s + 2, buf);
    }

    // merge: group B dumps partials to LDS; group A adds, normalizes, writes.
    // stride 44 floats/lane (16B-aligned, breaks pow2 bank pattern).
    float* M = (float*)&L[0][0];
    const int mb = (qw * 64 + lane) * 44;
    if (grp == 1) {
        #pragma unroll
        for (int g = 0; g < 2; ++g) {
            #pragma unroll
            for (int dt = 0; dt < 4; ++dt)
                *(f32x4*)&M[mb + (g * 4 + dt) * 4] = o[g][dt];
            *(f32x4*)&M[mb + 32 + g * 4] = ol[g];
        }
    }
    __syncthreads();
    if (grp == 0) {
        #pragma unroll
        for (int g = 0; g < 2; ++g) {
            #pragma unroll
            for (int dt = 0; dt < 4; ++dt)
                o[g][dt] += *(const f32x4*)&M[mb + (g * 4 + dt) * 4];
            ol[g] += *(const f32x4*)&M[mb + 32 + g * 4];
        }
        #pragma unroll
        for (int g = 0; g < 2; ++g)
            #pragma unroll
            for (int r = 0; r < 4; ++r) {
                float inv = 1.f / ol[g][r];
                size_t row = (size_t)b * S_ + q0 + qw * 32 + g * 16 + quad * 4 + r;
                unsigned short* op = out + row * D_ + h * HD_;
                #pragma unroll
                for (int dt = 0; dt < 4; ++dt)
                    op[dt * 16 + m16] = f2bf(o[g][dt][r] * inv);
            }
    }
}

// ---------------------------------------------------------------------------
extern "C" void kernel_launch(void* const* d_in, const int* in_sizes, int n_in,
                              void* d_out, int out_size, void* d_ws, size_t ws_size,
                              hipStream_t stream) {
    const float* x     = (const float*)d_in[0];
    const float* w_qkv = (const float*)d_in[1];
    const float* w_out = (const float*)d_in[2];
    float* out = (float*)d_out;

    const size_t n_x = (size_t)B_ * S_ * D_;
    const size_t n_wqkv = (size_t)3 * D_ * D_;
    const size_t n_wout = (size_t)D_ * D_;

    unsigned short* xb    = (unsigned short*)d_ws;
    unsigned short* wqkvb = xb + n_x;
    unsigned short* woutb = wqkvb + n_wqkv;
    unsigned short* qkvb  = woutb + n_wout;                    // [B,S,3D]
    unsigned short* attnb = qkvb + (size_t)B_ * S_ * 3 * D_;   // [B,S,D]
    unsigned short* vtb   = attnb + n_x;                       // [B*H*64, S]

    dim3 blk(256);

    cvt_all<<<2048, blk, 0, stream>>>(x, w_qkv, w_out, xb, wqkvb, woutb);

    // qkv = x @ w_qkv^T : M=4096, N=3072, K=1024 (bf16 out)
    gemm_nt_b<128><<<dim3(3 * D_ / 128, B_ * S_ / 128), blk, 0, stream>>>(
        xb, wqkvb, qkvb, B_ * S_, 3 * D_, D_, 1);

    // V transpose for DMA-friendly attention staging
    transpose_v<<<1024, blk, 0, stream>>>(qkvb, vtb);

    // attention: 512 XCD-swizzled blocks, 8 waves (key-split 2x4x32q)
    attn_mfma<<<512, dim3(512), 0, stream>>>(qkvb, vtb, attnb);

    // out = attn_out @ w_out^T : M=4096, N=1024, K=1024 (fp32 out, BN=64)
    gemm_nt_b<64><<<dim3(D_ / 64, B_ * S_ / 128), blk, 0, stream>>>(
        attnb, woutb, out, B_ * S_, D_, D_, 0);
}